// Round 7
// baseline (1219.557 us; speedup 1.0000x reference)
//
#include <hip/hip_runtime.h>
#include <hip/hip_bf16.h>
#include <stdint.h>

// SNN: B=256 batch, T=1000 steps, F=128 in-feats, H=256 hidden, O=2 out.
constexpr int B = 256, T = 1000, F = 128, H = 256, O = 2;
constexpr float DT_TAU_MEM = 0.1f;   // DT * TAU_MEM_INV
constexpr float SYN_DECAY  = 0.8f;   // 1 - DT * TAU_SYN_INV
constexpr float V_THRESH   = 1.0f;

__device__ inline unsigned short f2bf(float f) {
  __hip_bfloat16 h = __float2bfloat16(f);
  return *reinterpret_cast<unsigned short*>(&h);
}
__device__ inline float bf2f(unsigned short u) {
  return __uint_as_float(((unsigned int)u) << 16);
}

// xw storage adapters. fp32 is the CORRECT path (R1 passed on it; bf16 xw
// rounding (~2e-3 per xt) deterministically flips spikes -> absmax 2.5).
// bf16 kept only as a fallback if ws_size is ever too small.
template <typename XT> struct XConv;
template <> struct XConv<float> {
  static __device__ inline float load(const float* p) { return *p; }
  static __device__ inline void store4(float* p, float a, float b, float c, float d) {
    *reinterpret_cast<float4*>(p) = make_float4(a, b, c, d);
  }
};
template <> struct XConv<__hip_bfloat16> {
  static __device__ inline float load(const __hip_bfloat16* p) {
    return bf2f(*reinterpret_cast<const unsigned short*>(p));
  }
  static __device__ inline void store4(__hip_bfloat16* p, float a, float b, float c, float d) {
    ushort4 u = make_ushort4(f2bf(a), f2bf(b), f2bf(c), f2bf(d));
    *reinterpret_cast<ushort4*>(p) = u;
  }
};

// ---------------------------------------------------------------------------
// w_rec [h][k] -> wTz [k][h] fp32, 257 rows (row 256 = zeros, target of
// clamped speculative gather slots). Rows 0..255 identical to R1's wT.
// ---------------------------------------------------------------------------
__global__ void transpose_wrec(const float* __restrict__ w, float* __restrict__ wTz) {
  int k = blockIdx.x;
  int h = threadIdx.x;
  wTz[k * H + h] = (k < H) ? w[h * H + k] : 0.f;
}

// ---------------------------------------------------------------------------
// fp32 VALU GEMM — Round-1 arithmetic VERBATIM (passed, absmax 0.0): per
// output one sequential fp32 fma chain over k=0..127, stored fp32 (no
// rounding). DO NOT alter the inner loop's association.
// ---------------------------------------------------------------------------
template <typename XT>
__global__ __launch_bounds__(256) void gemm_xw(const float* __restrict__ x,
                                               const float* __restrict__ w_in,
                                               XT* __restrict__ xw) {
  constexpr int K = 128;
  constexpr int SA = 68;  // padded LDS row stride (floats)
  __shared__ float As[K][SA];
  __shared__ float Bs[K][SA];

  const int m0 = blockIdx.x * 64;
  const int n0 = blockIdx.y * 64;
  const int tid = threadIdx.x;

  {
    const int r  = tid >> 2;   // 0..63
    const int cq = tid & 3;    // 0..3
    const float* xa = x    + (size_t)(m0 + r) * K;
    const float* xb = w_in + (size_t)(n0 + r) * K;
#pragma unroll
    for (int j = 0; j < 8; ++j) {
      const int c = (cq + (j << 2)) << 2;
      float4 av = *reinterpret_cast<const float4*>(xa + c);
      float4 bv = *reinterpret_cast<const float4*>(xb + c);
      As[c + 0][r] = av.x; As[c + 1][r] = av.y; As[c + 2][r] = av.z; As[c + 3][r] = av.w;
      Bs[c + 0][r] = bv.x; Bs[c + 1][r] = bv.y; Bs[c + 2][r] = bv.z; Bs[c + 3][r] = bv.w;
    }
  }
  __syncthreads();

  const int tn = (tid & 15) << 2;
  const int tm = (tid >> 4) << 2;
  float acc[4][4] = {};

#pragma unroll 16
  for (int k = 0; k < K; ++k) {
    float4 a = *reinterpret_cast<const float4*>(&As[k][tm]);
    float4 b = *reinterpret_cast<const float4*>(&Bs[k][tn]);
    acc[0][0] += a.x * b.x; acc[0][1] += a.x * b.y; acc[0][2] += a.x * b.z; acc[0][3] += a.x * b.w;
    acc[1][0] += a.y * b.x; acc[1][1] += a.y * b.y; acc[1][2] += a.y * b.z; acc[1][3] += a.y * b.w;
    acc[2][0] += a.z * b.x; acc[2][1] += a.z * b.y; acc[2][2] += a.z * b.z; acc[2][3] += a.z * b.w;
    acc[3][0] += a.w * b.x; acc[3][1] += a.w * b.y; acc[3][2] += a.w * b.z; acc[3][3] += a.w * b.w;
  }

#pragma unroll
  for (int im = 0; im < 4; ++im) {
    XT* p = xw + (size_t)(m0 + tm + im) * H + (n0 + tn);
    XConv<XT>::store4(p, acc[im][0], acc[im][1], acc[im][2], acc[im][3]);
  }
}

// ---------------------------------------------------------------------------
// LIF scan — Round-1 structure (the passing one): atomicAdd spike list,
// cnt[2], 2 barriers/step, fp32 gathers from L2-resident wTz. Changes vs
// R1, both bit-neutral: (a) first 16 gathers issue as one speculative
// clamped batch (slots >= c hit zero row 256; 0+x == x; association
// replicates R1 exactly); (b) xt prefetch deepened 2 -> 4 (loads earlier,
// same values).
// ---------------------------------------------------------------------------
template <typename XT>
__global__ __launch_bounds__(256) void scan_lif(const XT* __restrict__ xw,
                                                const float* __restrict__ wTz,
                                                const float* __restrict__ fc_w,
                                                const float* __restrict__ fc_b,
                                                float* __restrict__ out) {
  __shared__ int   spk[2][H];
  __shared__ int   cnt[2];
  __shared__ float red[8];

  const int b = blockIdx.x;
  const int h = threadIdx.x;

  if (h < 2) cnt[h] = 0;
  __syncthreads();

  float v = 0.f, cur = 0.f;
  int spike_count = 0;

  const XT* xrow = xw + (size_t)b * T * H + h;
  float p0 = XConv<XT>::load(xrow + 0 * H);
  float p1 = XConv<XT>::load(xrow + 1 * H);
  float p2 = XConv<XT>::load(xrow + 2 * H);
  float p3 = XConv<XT>::load(xrow + 3 * H);

  for (int t = 0; t < T; ++t) {
    const int cb = t & 1, nb = cb ^ 1;
    const float xt = p0;
    p0 = p1; p1 = p2; p2 = p3;
    p3 = (t + 4 < T) ? XConv<XT>::load(xrow + (size_t)(t + 4) * H) : 0.f;

    const int c = cnt[cb];

    // speculative clamped batch: 16 indices, one L2 round-trip
    int idx[16];
#pragma unroll
    for (int j = 0; j < 16; ++j) idx[j] = (j < c) ? spk[cb][j] : 256;
    float wv_[16];
#pragma unroll
    for (int j = 0; j < 16; ++j) wv_[j] = wTz[(idx[j] << 8) + h];

    // R1-exact accumulation: groups of 4 as (w0+w1)+(w2+w3), then singles
    float rec = 0.f;
    const int full = ((c >> 2) < 4) ? (c >> 2) : 4;
#pragma unroll
    for (int g = 0; g < 4; ++g)
      if (g < full)
        rec += (wv_[4 * g + 0] + wv_[4 * g + 1]) + (wv_[4 * g + 2] + wv_[4 * g + 3]);
    const int tend = (c < 16) ? c : 16;
    for (int j = full << 2; j < tend; ++j) rec += wv_[j];

    if (c > 16) {            // continues R1's exact pattern from j=16
      int j = 16;
      for (; j + 4 <= c; j += 4) {
        const float w0 = wTz[(spk[cb][j + 0] << 8) + h];
        const float w1 = wTz[(spk[cb][j + 1] << 8) + h];
        const float w2 = wTz[(spk[cb][j + 2] << 8) + h];
        const float w3 = wTz[(spk[cb][j + 3] << 8) + h];
        rec += (w0 + w1) + (w2 + w3);
      }
      for (; j < c; ++j) rec += wTz[(spk[cb][j] << 8) + h];
    }

    // LIF update (R1 verbatim)
    const float v_dec = v + DT_TAU_MEM * (cur - v);
    const int z = v_dec > V_THRESH;
    v = z ? 0.f : v_dec;
    cur = cur * SYN_DECAY + xt + rec;
    spike_count += z;

    __syncthreads();  // all reads of spk[cb]/cnt[cb] done
    if (z) { int p = atomicAdd(&cnt[nb], 1); spk[nb][p] = h; }
    if (h == 0) cnt[cb] = 0;
    __syncthreads();  // new list + zero visible before next step
  }

  // readout (R1 verbatim): out[b][o] = sum_h count[h]*fc_w[o][h] + fc_b[o]
  const float cf = (float)spike_count;
#pragma unroll
  for (int o = 0; o < O; ++o) {
    float p = cf * fc_w[o * H + h];
#pragma unroll
    for (int off = 32; off > 0; off >>= 1) p += __shfl_down(p, off, 64);
    if ((h & 63) == 0) red[o * 4 + (h >> 6)] = p;
    __syncthreads();
  }
  if (h < O) {
    out[b * O + h] = (red[h * 4 + 0] + red[h * 4 + 1] + red[h * 4 + 2] + red[h * 4 + 3]) + fc_b[h];
  }
}

// ---------------------------------------------------------------------------
extern "C" void kernel_launch(void* const* d_in, const int* in_sizes, int n_in,
                              void* d_out, int out_size, void* d_ws, size_t ws_size,
                              hipStream_t stream) {
  const float* x     = (const float*)d_in[0];
  const float* w_in  = (const float*)d_in[1];
  const float* w_rec = (const float*)d_in[2];
  const float* fc_w  = (const float*)d_in[3];
  const float* fc_b  = (const float*)d_in[4];
  float* out = (float*)d_out;

  // workspace: [wTz fp32 257x256 = 263168 B][xw fp32 262 MB (preferred)]
  float* wTz = (float*)d_ws;
  const size_t wtz_bytes = (size_t)(H + 1) * H * sizeof(float);
  char* xw_base = (char*)d_ws + wtz_bytes;
  const size_t xw_elems = (size_t)B * T * H;
  const bool use_f32 = ws_size >= wtz_bytes + xw_elems * sizeof(float);

  transpose_wrec<<<H + 1, H, 0, stream>>>(w_rec, wTz);

  if (use_f32) {
    float* xw = (float*)xw_base;
    gemm_xw<float><<<dim3(B * T / 64, H / 64), 256, 0, stream>>>(x, w_in, xw);
    scan_lif<float><<<B, H, 0, stream>>>(xw, wTz, fc_w, fc_b, out);
  } else {
    __hip_bfloat16* xw = (__hip_bfloat16*)xw_base;
    gemm_xw<__hip_bfloat16><<<dim3(B * T / 64, H / 64), 256, 0, stream>>>(x, w_in, xw);
    scan_lif<__hip_bfloat16><<<B, H, 0, stream>>>(xw, wTz, fc_w, fc_b, out);
  }
}